// Round 11
// baseline (473.538 us; speedup 1.0000x reference)
//
#include <hip/hip_runtime.h>
#include <hip/hip_bf16.h>
#include <stdint.h>

#define B_ 4
#define H_ 160
#define W_ 160
#define HW_ 25600
#define PH_ 162
#define PHW_ 26244   // 162*162

typedef __hip_bfloat16 bf16;
typedef __attribute__((ext_vector_type(8))) short bf16x8;
typedef __attribute__((ext_vector_type(4))) float f32x4;

// ---------------- static workspace (module .bss) ----------------
// GROUP-PLANAR padded activation buffers: [B][g=8][162][162][8ch] bf16.
__device__ __align__(16) bf16 g_P1[6718464];  // Xnbr
__device__ __align__(16) bf16 g_P2[6718464];  // Xref
__device__ __align__(16) bf16 g_P3[6718464];  // A1
__device__ __align__(16) bf16 g_P4[6718464];  // A2
__device__ __align__(16) bf16 g_P5[6718464];  // F1
__device__ __align__(16) bf16 g_WB[516096];   // conv weights, fragment order
__device__ __align__(16) bf16 g_WD[73728];    // 2 x dcn weights, frag, K-permuted

__device__ __forceinline__ bf16* pbuf(int id) {
  if (id == 1) return g_P1;
  if (id == 2) return g_P2;
  if (id == 3) return g_P3;
  if (id == 4) return g_P4;
  return g_P5;
}

// XCD-aware bijective swizzle (grid multiple of 8).
__device__ __forceinline__ int xcdswz(int bx, int q) {
  return (bx & 7) * q + (bx >> 3);
}

// ---------------- weight prep: conv fragment order ----------------
// layout [cc][tap][nt(NTPB)][lane(64)][j(8)]
__global__ void prep_wfrag(const float* __restrict__ src, int off,
                           int OC, int CIN, int NB, int NTPB) {
  int i = blockIdx.x * 256 + threadIdx.x;
  int CC = CIN >> 5;
  int total = NB * CC * 9 * NTPB * 512;
  if (i >= total) return;
  int j = i & 7;
  int t = i >> 3;
  int lane = t & 63; t >>= 6;
  int nt = t % NTPB; t /= NTPB;
  int tap = t % 9; t /= 9;
  int cc = t % CC; int nb = t / CC;
  int oc = nb * (NTPB * 16) + nt * 16 + (lane & 15);
  int ci = cc * 32 + (lane >> 4) * 8 + j;
  float v = (oc < OC) ? src[(oc * CIN + ci) * 9 + tap] : 0.f;
  g_WB[off + i] = __float2bfloat16(v);
}

// dcn weights -> frag order with K-permutation k' = g*72 + kk*8 + c
__global__ void prep_wdcnfrag(const float* __restrict__ src, int off) {
  int i = blockIdx.x * 256 + threadIdx.x;
  if (i >= 36864) return;
  int j = i & 7;
  int t = i >> 3;
  int lane = t & 63; t >>= 6;
  int nt = t & 3; int kc = t >> 2;
  int kp = kc * 32 + (lane >> 4) * 8 + j;
  int oc = nt * 16 + (lane & 15);
  int g = kp / 72, r = kp - g * 72;
  int kk = r >> 3, c = r & 7;
  g_WD[off + i] = __float2bfloat16(src[oc * 576 + g * 72 + c * 9 + kk]);
}

// ---------------- NCHW f32 -> group-planar padded bf16 ----------------
// grid (160, B): one image row per block.
__global__ __launch_bounds__(256)
void nchw2gp_pad(const float* __restrict__ in, int out_id) {
  __shared__ float T[64][161];
  int tid = threadIdx.x;
  int y = blockIdx.x, b = blockIdx.y;
#pragma unroll
  for (int it = 0; it < 10; ++it) {
    int i = it * 256 + tid;                 // 2560 float4 loads
    int c = i / 40, xq = i - c * 40;
    float4 v = *(const float4*)&in[((size_t)(b * 64 + c) * H_ + y) * W_ + xq * 4];
    T[c][xq * 4 + 0] = v.x; T[c][xq * 4 + 1] = v.y;
    T[c][xq * 4 + 2] = v.z; T[c][xq * 4 + 3] = v.w;
  }
  __syncthreads();
  bf16* ob = pbuf(out_id) + (size_t)b * PHW_ * 64;
  int g = tid >> 5;
#pragma unroll
  for (int it = 0; it < 5; ++it) {
    int px = it * 32 + (tid & 31);
    bf16 t8[8];
#pragma unroll
    for (int j = 0; j < 8; ++j) t8[j] = __float2bfloat16(T[g * 8 + j][px]);
    *(uint4*)(ob + ((size_t)g * PHW_ + (size_t)(y + 1) * PH_ + px + 1) * 8) = *(const uint4*)t8;
  }
}

// ---------------- implicit-GEMM conv3x3: LDS-staged input tile ----------------
// Block: 2 rows x 32 px, 4 waves, wave w owns oc [w*16, w*16+16).
// Input tile (4 rows x 34 px x CH) staged ONCE in LDS from group-planar src;
// XOR swizzle (px&7)<<4 keeps ds_read_b128 16B-aligned at <=2-way banking.
template<int CC>
__global__ __launch_bounds__(256, 4)
void conv_nhwc(int in1_id, int in2_id, int ccsplit, int woff,
               const float* __restrict__ bias, int out_id)
{
  constexpr int CH = CC * 32;            // input channels
  constexpr int CH8 = CH / 8;            // 16B chunks per px
  constexpr int NCHUNK = CH8 * 136;      // staging chunks (c8-major, px fastest)
  constexpr int XS_BYTES = 4 * 34 * CH * 2;
  constexpr int SH_BYTES = (XS_BYTES > 64 * 66 * 2) ? XS_BYTES : 64 * 66 * 2;
  __shared__ __align__(16) char SH[SH_BYTES];
  char* XS = SH;                         // staged input, swizzled
  bf16* TS = (bf16*)SH;                  // epilogue transpose [64 px][66]

  int tid = threadIdx.x;
  int w = tid >> 6, L = tid & 63, lm = L & 15;
  int k0 = (L >> 4) * 8;
  int r4 = (L >> 4) * 4;
  int bx = xcdswz(blockIdx.x, 50);
  int b = blockIdx.y;
  int y0 = (bx / 5) * 2, x0 = (bx % 5) * 32;
  const bf16* s1 = pbuf(in1_id) + (size_t)b * PHW_ * 64;
  const bf16* s2 = pbuf(in2_id) + (size_t)b * PHW_ * 64;
  const bf16* wl = g_WB + woff + L * 8;

  // ---- stage input tile: rows y0..y0+3 (padded coords), px x0..x0+33 ----
  for (int i = tid; i < NCHUNK; i += 256) {
    int c8 = i / 136;
    int rem = i - c8 * 136;
    int r = rem / 34, px = rem - r * 34;
    const bf16* sbuf = (c8 < ccsplit * 4) ? s1 : s2;
    int pl = (c8 < ccsplit * 4) ? c8 : c8 - ccsplit * 4;
    uint4 v = *(const uint4*)(sbuf +
        ((size_t)pl * PHW_ + (size_t)(y0 + r) * PH_ + x0 + px) * 8);
    int lb = ((r * 34 + px) * CH + c8 * 8) * 2;
    lb ^= (px & 7) << 4;
    *(uint4*)(XS + lb) = v;
  }
  __syncthreads();

  f32x4 acc[4];
#pragma unroll
  for (int nf = 0; nf < 4; ++nf) acc[nf] = (f32x4)0.f;

#pragma unroll
  for (int cc = 0; cc < CC; ++cc) {
#pragma unroll
    for (int tap = 0; tap < 9; ++tap) {
      const int dy = tap / 3, dx = tap - dy * 3;
      const int ks = cc * 9 + tap;
      bf16x8 wf = *(const bf16x8*)(wl + (size_t)(ks * 4 + w) * 512);
#pragma unroll
      for (int nf = 0; nf < 4; ++nf) {
        int ri = nf >> 1, ci = nf & 1;
        int px = ci * 16 + dx + lm;
        int lb = (((ri + dy) * 34 + px) * CH + cc * 32 + k0) * 2;
        lb ^= (px & 7) << 4;
        bf16x8 af = *(const bf16x8*)(XS + lb);
        acc[nf] = __builtin_amdgcn_mfma_f32_16x16x32_bf16(wf, af, acc[nf], 0, 0, 0);
      }
    }
  }

  // ---- transpose 64px x 64ch through LDS (aliases XS); group-planar stores ----
  __syncthreads();
  int ocb = w * 16 + r4;
#pragma unroll
  for (int nf = 0; nf < 4; ++nf) {
    int ri = nf >> 1, ci = nf & 1;
    int p = ri * 32 + ci * 16 + lm;
    bf16 t[4];
#pragma unroll
    for (int r = 0; r < 4; ++r) {
      float v = acc[nf][r] + bias[ocb + r];
      v = v > 0.f ? v : 0.1f * v;
      t[r] = __float2bfloat16(v);
    }
    *(uint2*)&TS[p * 66 + ocb] = *(const uint2*)t;
  }
  __syncthreads();
  bf16* ob = pbuf(out_id) + (size_t)b * PHW_ * 64;
#pragma unroll
  for (int it = 0; it < 2; ++it) {
    int i = it * 256 + tid;
    int pl = i >> 6, p = i & 63;
    int ri = p >> 5, xo = p & 31;
    *(uint4*)(ob + ((size_t)pl * PHW_ + (size_t)(y0 + 1 + ri) * PH_ + x0 + 1 + xo) * 8) =
        *(const uint4*)&TS[p * 66 + pl * 8];
  }
}

// ---------------- fused offset-conv + modulated deformable conv ----------------
// grid: (800, B). block 256. One 1x32 px tile.
// A2 tile (3 rows x 34 px x 64ch, 13KB) staged ONCE in LDS -> phase 0's 72
// divergent global af loads per wave become ds_reads (TA relief; R10 showed
// the wall is vector-memory transaction rate, not occupancy).
// Phase 0 split into two oc-halves; coS [112][34] f32 lives after A2S.
// Gather/MFMA split into two gk-halves (R8 structure).
#define LO16(u) __uint_as_float((u) << 16)
#define HI16(u) __uint_as_float((u) & 0xffff0000u)

__global__ __launch_bounds__(256, 5)
void dcn_k(int x_id, int a2_id, int co_woff, const float* __restrict__ co_bias,
           int wd_off, const float* __restrict__ bias,
           float* __restrict__ outp, int xt_out_id)
{
  const bf16* xT = pbuf(x_id);
  const bf16* WD = g_WD + wd_off;               // [18][4][64][8]
  __shared__ __align__(16) char SHD[28288];
  char* A2S = SHD;                              // [3][34][64] bf16 swz, 13056B
  float* coS = (float*)(SHD + 13056);           // [112][34] f32, 15232B
  bf16* vS = (bf16*)SHD;                        // [32][332] (gather phases)
  int tid = threadIdx.x;
  int b = blockIdx.y;
  int bx = xcdswz(blockIdx.x, 100);
  int h = bx / 5;
  int w0 = (bx % 5) * 32;
  int w = tid >> 6, L = tid & 63, lm = L & 15;
  int q = L >> 4;
  int k0 = q * 8, r4 = q * 4;
  const bf16* xb = xT + (size_t)b * PHW_ * 64;
  const bf16* a2 = pbuf(a2_id) + (size_t)b * PHW_ * 64;
  const bf16* wl = g_WB + co_woff + L * 8;
  float oy[9], ox[9], mk[9];

  // ---- stage A2 tile: padded rows h..h+2, px w0..w0+33, all 8 planes ----
  for (int i = tid; i < 816; i += 256) {
    int c8 = i / 102;
    int rem = i - c8 * 102;
    int r = rem / 34, px = rem - r * 34;
    uint4 v = *(const uint4*)(a2 +
        ((size_t)c8 * PHW_ + (size_t)(h + r) * PH_ + w0 + px) * 8);
    int lb = ((r * 34 + px) * 64 + c8 * 8) * 2;
    lb ^= (px & 7) << 4;
    *(uint4*)(A2S + lb) = v;
  }
  __syncthreads();

  // ---- phase 0a: CO oc 0..111 (nt 0..6), af from LDS ----
  {
    f32x4 cacc[2][2];
#pragma unroll
    for (int ci = 0; ci < 2; ++ci)
#pragma unroll
      for (int oh = 0; oh < 2; ++oh) cacc[ci][oh] = (f32x4)0.f;
#pragma unroll
    for (int cc = 0; cc < 2; ++cc) {
#pragma unroll
      for (int tap = 0; tap < 9; ++tap) {
        const int dy = tap / 3, dx = tap - dy * 3;
        const int ks = cc * 9 + tap;
        int pxa = dx + lm, pxb = 16 + dx + lm;
        int lba = (((dy * 34 + pxa) * 64 + (cc * 4 + q) * 8) * 2) ^ ((pxa & 7) << 4);
        int lbb = (((dy * 34 + pxb) * 64 + (cc * 4 + q) * 8) * 2) ^ ((pxb & 7) << 4);
        bf16x8 af0 = *(const bf16x8*)(A2S + lba);
        bf16x8 af1 = *(const bf16x8*)(A2S + lbb);
#pragma unroll
        for (int oh = 0; oh < 2; ++oh) {
          int nt = oh * 4 + w;
          if (nt < 7) {
            bf16x8 wf = *(const bf16x8*)(wl + (size_t)(ks * 14 + nt) * 512);
            cacc[0][oh] = __builtin_amdgcn_mfma_f32_16x16x32_bf16(wf, af0, cacc[0][oh], 0, 0, 0);
            cacc[1][oh] = __builtin_amdgcn_mfma_f32_16x16x32_bf16(wf, af1, cacc[1][oh], 0, 0, 0);
          }
        }
      }
    }
#pragma unroll
    for (int ci = 0; ci < 2; ++ci)
#pragma unroll
      for (int oh = 0; oh < 2; ++oh) {
        int nt = oh * 4 + w;
        if (nt < 7) {
#pragma unroll
          for (int r = 0; r < 4; ++r) {
            int oc = nt * 16 + r4 + r;       // <= 111, never sigmoid
            coS[oc * 34 + ci * 16 + lm] = cacc[ci][oh][r] + co_bias[oc];
          }
        }
      }
  }
  __syncthreads();
  // oy/ox for taps 0..6 live in channels < 112
#pragma unroll
  for (int t = 0; t < 7; ++t) {
    int idx = t * 256 + tid;
    int gk = idx >> 5, p = idx & 31;
    oy[t] = coS[(gk * 2) * 34 + p];
    ox[t] = coS[(gk * 2 + 1) * 34 + p];
  }
  __syncthreads();

  // ---- phase 0b: CO oc 112..215 (nt 7..13), af from LDS ----
  {
    f32x4 cacc[2][2];
#pragma unroll
    for (int ci = 0; ci < 2; ++ci)
#pragma unroll
      for (int oh = 0; oh < 2; ++oh) cacc[ci][oh] = (f32x4)0.f;
#pragma unroll
    for (int cc = 0; cc < 2; ++cc) {
#pragma unroll
      for (int tap = 0; tap < 9; ++tap) {
        const int dy = tap / 3, dx = tap - dy * 3;
        const int ks = cc * 9 + tap;
        int pxa = dx + lm, pxb = 16 + dx + lm;
        int lba = (((dy * 34 + pxa) * 64 + (cc * 4 + q) * 8) * 2) ^ ((pxa & 7) << 4);
        int lbb = (((dy * 34 + pxb) * 64 + (cc * 4 + q) * 8) * 2) ^ ((pxb & 7) << 4);
        bf16x8 af0 = *(const bf16x8*)(A2S + lba);
        bf16x8 af1 = *(const bf16x8*)(A2S + lbb);
#pragma unroll
        for (int oh = 0; oh < 2; ++oh) {
          int nt = 7 + oh * 4 + w;
          if (nt < 14) {
            bf16x8 wf = *(const bf16x8*)(wl + (size_t)(ks * 14 + nt) * 512);
            cacc[0][oh] = __builtin_amdgcn_mfma_f32_16x16x32_bf16(wf, af0, cacc[0][oh], 0, 0, 0);
            cacc[1][oh] = __builtin_amdgcn_mfma_f32_16x16x32_bf16(wf, af1, cacc[1][oh], 0, 0, 0);
          }
        }
      }
    }
#pragma unroll
    for (int ci = 0; ci < 2; ++ci)
#pragma unroll
      for (int oh = 0; oh < 2; ++oh) {
        int nt = 7 + oh * 4 + w;
        if (nt < 14) {
#pragma unroll
          for (int r = 0; r < 4; ++r) {
            int oc = nt * 16 + r4 + r;       // 112..223
            if (oc < 216) {
              float v = cacc[ci][oh][r] + co_bias[oc];
              if (oc >= 144) v = 1.f / (1.f + __expf(-v));
              coS[(oc - 112) * 34 + ci * 16 + lm] = v;
            }
          }
        }
      }
  }
  __syncthreads();
  // taps 7..8 oy/ox (channels 112..143) + all masks (channels 144..215)
#pragma unroll
  for (int t = 7; t < 9; ++t) {
    int idx = t * 256 + tid;
    int gk = idx >> 5, p = idx & 31;
    oy[t] = coS[(gk * 2 - 112) * 34 + p];
    ox[t] = coS[(gk * 2 + 1 - 112) * 34 + p];
  }
#pragma unroll
  for (int t = 0; t < 9; ++t) {
    int idx = t * 256 + tid;
    int gk = idx >> 5, p = idx & 31;
    mk[t] = coS[(32 + gk) * 34 + p];
  }
  __syncthreads();

  int mt = w & 1;
  int nb2 = (w >> 1) * 2;
  f32x4 acc2[2];
  acc2[0] = (f32x4)0.f; acc2[1] = (f32x4)0.f;

#define GATHER(t, gkbase) { \
    int idx = (t) * 256 + tid; \
    int gk = idx >> 5, p = idx & 31; \
    int g = gk / 9, kk = gk - g * 9; \
    float pyf = oy[t] + (float)(kk / 3 - 1 + h); \
    float pxf = ox[t] + (float)(kk % 3 - 1 + w0 + p); \
    float y0f = floorf(pyf), x0f = floorf(pxf); \
    float ly = pyf - y0f, lx = pxf - x0f; \
    int iy0 = (int)y0f, ix0 = (int)x0f; \
    int iy1 = iy0 + 1, ix1 = ix0 + 1; \
    float mask = mk[t]; \
    float w00 = (1.f - ly) * (1.f - lx) * mask; \
    float w01 = (1.f - ly) * lx * mask; \
    float w10 = ly * (1.f - lx) * mask; \
    float w11 = ly * lx * mask; \
    if (iy0 < 0 || iy0 >= H_) { w00 = 0.f; w01 = 0.f; } \
    if (iy1 < 0 || iy1 >= H_) { w10 = 0.f; w11 = 0.f; } \
    if (ix0 < 0 || ix0 >= W_) { w00 = 0.f; w10 = 0.f; } \
    if (ix1 < 0 || ix1 >= W_) { w01 = 0.f; w11 = 0.f; } \
    int cy0 = min(max(iy0, 0), H_ - 1), cy1 = min(max(iy1, 0), H_ - 1); \
    int cx0 = min(max(ix0, 0), W_ - 1), cx1 = min(max(ix1, 0), W_ - 1); \
    const bf16* gp = xb + (size_t)g * PHW_ * 8; \
    uint4 u00 = *(const uint4*)(gp + ((size_t)(cy0 + 1) * PH_ + cx0 + 1) * 8); \
    uint4 u01 = *(const uint4*)(gp + ((size_t)(cy0 + 1) * PH_ + cx1 + 1) * 8); \
    uint4 u10 = *(const uint4*)(gp + ((size_t)(cy1 + 1) * PH_ + cx0 + 1) * 8); \
    uint4 u11 = *(const uint4*)(gp + ((size_t)(cy1 + 1) * PH_ + cx1 + 1) * 8); \
    bf16 tmp[8]; \
    { float vlo = w00 * LO16(u00.x) + w01 * LO16(u01.x) + w10 * LO16(u10.x) + w11 * LO16(u11.x); \
      float vhi = w00 * HI16(u00.x) + w01 * HI16(u01.x) + w10 * HI16(u10.x) + w11 * HI16(u11.x); \
      tmp[0] = __float2bfloat16(vlo); tmp[1] = __float2bfloat16(vhi); } \
    { float vlo = w00 * LO16(u00.y) + w01 * LO16(u01.y) + w10 * LO16(u10.y) + w11 * LO16(u11.y); \
      float vhi = w00 * HI16(u00.y) + w01 * HI16(u01.y) + w10 * HI16(u10.y) + w11 * HI16(u11.y); \
      tmp[2] = __float2bfloat16(vlo); tmp[3] = __float2bfloat16(vhi); } \
    { float vlo = w00 * LO16(u00.z) + w01 * LO16(u01.z) + w10 * LO16(u10.z) + w11 * LO16(u11.z); \
      float vhi = w00 * HI16(u00.z) + w01 * HI16(u01.z) + w10 * HI16(u10.z) + w11 * HI16(u11.z); \
      tmp[4] = __float2bfloat16(vlo); tmp[5] = __float2bfloat16(vhi); } \
    { float vlo = w00 * LO16(u00.w) + w01 * LO16(u01.w) + w10 * LO16(u10.w) + w11 * LO16(u11.w); \
      float vhi = w00 * HI16(u00.w) + w01 * HI16(u01.w) + w10 * HI16(u10.w) + w11 * HI16(u11.w); \
      tmp[6] = __float2bfloat16(vlo); tmp[7] = __float2bfloat16(vhi); } \
    *(uint4*)&vS[p * 332 + (gk - (gkbase)) * 8] = *(const uint4*)tmp; \
  }

  // ---- half 1: gk 0..39 (taps 0..4), MFMA kc 0..9 ----
#pragma unroll
  for (int t = 0; t < 5; ++t) GATHER(t, 0)
  __syncthreads();
#pragma unroll
  for (int kc = 0; kc < 10; ++kc) {
    bf16x8 a = *(const bf16x8*)&vS[(mt * 16 + lm) * 332 + (kc * 4 + q) * 8];
#pragma unroll
    for (int i = 0; i < 2; ++i) {
      bf16x8 bw = *(const bf16x8*)(WD + ((kc * 4 + nb2 + i) * 64 + L) * 8);
      acc2[i] = __builtin_amdgcn_mfma_f32_16x16x32_bf16(a, bw, acc2[i], 0, 0, 0);
    }
  }
  __syncthreads();

  // ---- half 2: gk 40..71 (taps 5..8), MFMA kc 10..17 ----
#pragma unroll
  for (int t = 5; t < 9; ++t) GATHER(t, 40)
  __syncthreads();
#pragma unroll
  for (int kc = 10; kc < 18; ++kc) {
    bf16x8 a = *(const bf16x8*)&vS[(mt * 16 + lm) * 332 + ((kc * 4 + q) - 40) * 8];
#pragma unroll
    for (int i = 0; i < 2; ++i) {
      bf16x8 bw = *(const bf16x8*)(WD + ((kc * 4 + nb2 + i) * 64 + L) * 8);
      acc2[i] = __builtin_amdgcn_mfma_f32_16x16x32_bf16(a, bw, acc2[i], 0, 0, 0);
    }
  }
  __syncthreads();
#undef GATHER

  // ---- epilogue through LDS ----
  float* outS = (float*)SHD;          // [64 oc][33]
#pragma unroll
  for (int i = 0; i < 2; ++i)
#pragma unroll
    for (int r = 0; r < 4; ++r) {
      int oc = (nb2 + i) * 16 + lm;
      int px = mt * 16 + (L >> 4) * 4 + r;
      outS[oc * 33 + px] = acc2[i][r];
    }
  __syncthreads();
  if (outp) {
    for (int i = tid; i < 2048; i += 256) {
      int oc = i >> 5, p2 = i & 31;
      float v = outS[oc * 33 + p2] + bias[oc];
      v = v > 0.f ? v : 0.1f * v;
      outp[((size_t)(b * 64 + oc) * H_ + h) * W_ + w0 + p2] = v;
    }
  }
  if (xt_out_id) {
    bf16* xt = pbuf(xt_out_id) + (size_t)b * PHW_ * 64;
    int pl = tid >> 5, p2 = tid & 31;
    bf16 t8[8];
#pragma unroll
    for (int j = 0; j < 8; ++j) {
      int c = pl * 8 + j;
      float v = outS[c * 33 + p2] + bias[c];
      v = v > 0.f ? v : 0.1f * v;
      t8[j] = __float2bfloat16(v);
    }
    *(uint4*)(xt + ((size_t)pl * PHW_ + (size_t)(h + 1) * PH_ + w0 + p2 + 1) * 8) =
        *(const uint4*)t8;
  }
}

extern "C" void kernel_launch(void* const* d_in, const int* in_sizes, int n_in,
                              void* d_out, int out_size, void* d_ws, size_t ws_size,
                              hipStream_t stream) {
  (void)in_sizes; (void)n_in; (void)out_size; (void)d_ws; (void)ws_size;
  const float* nbr    = (const float*)d_in[0];
  const float* ref    = (const float*)d_in[1];
  const float* w_off1 = (const float*)d_in[2];
  const float* b_off1 = (const float*)d_in[3];
  const float* w_off2 = (const float*)d_in[4];
  const float* b_off2 = (const float*)d_in[5];
  const float* w_co   = (const float*)d_in[6];
  const float* b_co   = (const float*)d_in[7];
  const float* w_dcn  = (const float*)d_in[8];
  const float* b_dcn  = (const float*)d_in[9];
  const float* w_coff1= (const float*)d_in[10];
  const float* b_coff1= (const float*)d_in[11];
  const float* w_coff2= (const float*)d_in[12];
  const float* b_coff2= (const float*)d_in[13];
  const float* w_cco  = (const float*)d_in[14];
  const float* b_cco  = (const float*)d_in[15];
  const float* w_cdcn = (const float*)d_in[16];
  const float* b_cdcn = (const float*)d_in[17];

  // conv weights: off1 [0,73728) off2 [73728,110592) co@NTPB14 [110592,239616)
  //               coff1 [239616,313344) coff2 [313344,350208) cco@NTPB14 [350208,479232)
  prep_wfrag<<<288, 256, 0, stream>>>(w_off1, 0, 64, 128, 1, 4);
  prep_wfrag<<<144, 256, 0, stream>>>(w_off2, 73728, 64, 64, 1, 4);
  prep_wfrag<<<504, 256, 0, stream>>>(w_co, 110592, 216, 64, 1, 14);
  prep_wfrag<<<288, 256, 0, stream>>>(w_coff1, 239616, 64, 128, 1, 4);
  prep_wfrag<<<144, 256, 0, stream>>>(w_coff2, 313344, 64, 64, 1, 4);
  prep_wfrag<<<504, 256, 0, stream>>>(w_cco, 350208, 216, 64, 1, 14);
  prep_wdcnfrag<<<144, 256, 0, stream>>>(w_dcn, 0);
  prep_wdcnfrag<<<144, 256, 0, stream>>>(w_cdcn, 36864);

  dim3 blk(256);
  float* out = (float*)d_out;
  // group-planar padded inputs
  nchw2gp_pad<<<dim3(160, 4), blk, 0, stream>>>(nbr, 1);
  nchw2gp_pad<<<dim3(160, 4), blk, 0, stream>>>(ref, 2);
  // A1 = lrelu(conv(cat(nbr,ref))); A2 = lrelu(conv(A1))
  conv_nhwc<4><<<dim3(400, 4), blk, 0, stream>>>(1, 2, 2, 0, b_off1, 3);
  conv_nhwc<2><<<dim3(400, 4), blk, 0, stream>>>(3, 3, 2, 73728, b_off2, 4);
  // F1 = lrelu(dcn(Xnbr, conv(A2)))  (fused CO)
  dcn_k<<<dim3(800, 4), blk, 0, stream>>>(1, 4, 110592, b_co, 0, b_dcn, nullptr, 5);
  // cascade
  conv_nhwc<4><<<dim3(400, 4), blk, 0, stream>>>(5, 2, 2, 239616, b_coff1, 3);
  conv_nhwc<2><<<dim3(400, 4), blk, 0, stream>>>(3, 3, 2, 313344, b_coff2, 4);
  // out = lrelu(dcn(F1, conv(A2')))  (fused CO)
  dcn_k<<<dim3(800, 4), blk, 0, stream>>>(5, 4, 350208, b_cco, 36864, b_cdcn, out, 0);
}

// Round 12
// 437.774 us; speedup vs baseline: 1.0817x; 1.0817x over previous
//
#include <hip/hip_runtime.h>
#include <hip/hip_bf16.h>
#include <stdint.h>

#define B_ 4
#define H_ 160
#define W_ 160
#define HW_ 25600
#define PH_ 162
#define PHW_ 26244   // 162*162

typedef __hip_bfloat16 bf16;
typedef __attribute__((ext_vector_type(8))) short bf16x8;
typedef __attribute__((ext_vector_type(4))) float f32x4;

// ---------------- static workspace (module .bss) ----------------
// GROUP-PLANAR padded activation buffers: [B][g=8][162][162][8ch] bf16.
__device__ __align__(16) bf16 g_P1[6718464];  // Xnbr
__device__ __align__(16) bf16 g_P2[6718464];  // Xref
__device__ __align__(16) bf16 g_P3[6718464];  // A1
__device__ __align__(16) bf16 g_P4[6718464];  // A2
__device__ __align__(16) bf16 g_P5[6718464];  // F1
__device__ __align__(16) bf16 g_WB[516096];   // conv weights, fragment order
__device__ __align__(16) bf16 g_WD[73728];    // 2 x dcn weights, frag, K-permuted

__device__ __forceinline__ bf16* pbuf(int id) {
  if (id == 1) return g_P1;
  if (id == 2) return g_P2;
  if (id == 3) return g_P3;
  if (id == 4) return g_P4;
  return g_P5;
}

// XCD-aware bijective swizzle (grid multiple of 8).
__device__ __forceinline__ int xcdswz(int bx, int q) {
  return (bx & 7) * q + (bx >> 3);
}

// ---------------- weight prep: conv fragment order ----------------
// layout [cc][tap][nt(NTPB)][lane(64)][j(8)]
__global__ void prep_wfrag(const float* __restrict__ src, int off,
                           int OC, int CIN, int NB, int NTPB) {
  int i = blockIdx.x * 256 + threadIdx.x;
  int CC = CIN >> 5;
  int total = NB * CC * 9 * NTPB * 512;
  if (i >= total) return;
  int j = i & 7;
  int t = i >> 3;
  int lane = t & 63; t >>= 6;
  int nt = t % NTPB; t /= NTPB;
  int tap = t % 9; t /= 9;
  int cc = t % CC; int nb = t / CC;
  int oc = nb * (NTPB * 16) + nt * 16 + (lane & 15);
  int ci = cc * 32 + (lane >> 4) * 8 + j;
  float v = (oc < OC) ? src[(oc * CIN + ci) * 9 + tap] : 0.f;
  g_WB[off + i] = __float2bfloat16(v);
}

// dcn weights -> frag order with K-permutation k' = g*72 + kk*8 + c
__global__ void prep_wdcnfrag(const float* __restrict__ src, int off) {
  int i = blockIdx.x * 256 + threadIdx.x;
  if (i >= 36864) return;
  int j = i & 7;
  int t = i >> 3;
  int lane = t & 63; t >>= 6;
  int nt = t & 3; int kc = t >> 2;
  int kp = kc * 32 + (lane >> 4) * 8 + j;
  int oc = nt * 16 + (lane & 15);
  int g = kp / 72, r = kp - g * 72;
  int kk = r >> 3, c = r & 7;
  g_WD[off + i] = __float2bfloat16(src[oc * 576 + g * 72 + c * 9 + kk]);
}

// ---------------- NCHW f32 -> group-planar padded bf16 ----------------
// grid (160, B): one image row per block.
__global__ __launch_bounds__(256)
void nchw2gp_pad(const float* __restrict__ in, int out_id) {
  __shared__ float T[64][161];
  int tid = threadIdx.x;
  int y = blockIdx.x, b = blockIdx.y;
#pragma unroll
  for (int it = 0; it < 10; ++it) {
    int i = it * 256 + tid;                 // 2560 float4 loads
    int c = i / 40, xq = i - c * 40;
    float4 v = *(const float4*)&in[((size_t)(b * 64 + c) * H_ + y) * W_ + xq * 4];
    T[c][xq * 4 + 0] = v.x; T[c][xq * 4 + 1] = v.y;
    T[c][xq * 4 + 2] = v.z; T[c][xq * 4 + 3] = v.w;
  }
  __syncthreads();
  bf16* ob = pbuf(out_id) + (size_t)b * PHW_ * 64;
  int g = tid >> 5;
#pragma unroll
  for (int it = 0; it < 5; ++it) {
    int px = it * 32 + (tid & 31);
    bf16 t8[8];
#pragma unroll
    for (int j = 0; j < 8; ++j) t8[j] = __float2bfloat16(T[g * 8 + j][px]);
    *(uint4*)(ob + ((size_t)g * PHW_ + (size_t)(y + 1) * PH_ + px + 1) * 8) = *(const uint4*)t8;
  }
}

// ---------------- implicit-GEMM conv3x3: LDS-staged input tile ----------------
// Block: 2 rows x 32 px, 4 waves, wave w owns oc [w*16, w*16+16).
// Input tile (4 rows x 34 px x CH) staged ONCE in LDS from group-planar src;
// XOR swizzle (px&7)<<4 keeps ds_read_b128 16B-aligned at <=2-way banking.
template<int CC>
__global__ __launch_bounds__(256, 4)
void conv_nhwc(int in1_id, int in2_id, int ccsplit, int woff,
               const float* __restrict__ bias, int out_id)
{
  constexpr int CH = CC * 32;            // input channels
  constexpr int CH8 = CH / 8;            // 16B chunks per px
  constexpr int NCHUNK = CH8 * 136;      // staging chunks (c8-major, px fastest)
  constexpr int XS_BYTES = 4 * 34 * CH * 2;
  constexpr int SH_BYTES = (XS_BYTES > 64 * 66 * 2) ? XS_BYTES : 64 * 66 * 2;
  __shared__ __align__(16) char SH[SH_BYTES];
  char* XS = SH;                         // staged input, swizzled
  bf16* TS = (bf16*)SH;                  // epilogue transpose [64 px][66]

  int tid = threadIdx.x;
  int w = tid >> 6, L = tid & 63, lm = L & 15;
  int k0 = (L >> 4) * 8;
  int r4 = (L >> 4) * 4;
  int bx = xcdswz(blockIdx.x, 50);
  int b = blockIdx.y;
  int y0 = (bx / 5) * 2, x0 = (bx % 5) * 32;
  const bf16* s1 = pbuf(in1_id) + (size_t)b * PHW_ * 64;
  const bf16* s2 = pbuf(in2_id) + (size_t)b * PHW_ * 64;
  const bf16* wl = g_WB + woff + L * 8;

  // ---- stage input tile: rows y0..y0+3 (padded coords), px x0..x0+33 ----
  for (int i = tid; i < NCHUNK; i += 256) {
    int c8 = i / 136;
    int rem = i - c8 * 136;
    int r = rem / 34, px = rem - r * 34;
    const bf16* sbuf = (c8 < ccsplit * 4) ? s1 : s2;
    int pl = (c8 < ccsplit * 4) ? c8 : c8 - ccsplit * 4;
    uint4 v = *(const uint4*)(sbuf +
        ((size_t)pl * PHW_ + (size_t)(y0 + r) * PH_ + x0 + px) * 8);
    int lb = ((r * 34 + px) * CH + c8 * 8) * 2;
    lb ^= (px & 7) << 4;
    *(uint4*)(XS + lb) = v;
  }
  __syncthreads();

  f32x4 acc[4];
#pragma unroll
  for (int nf = 0; nf < 4; ++nf) acc[nf] = (f32x4)0.f;

#pragma unroll
  for (int cc = 0; cc < CC; ++cc) {
#pragma unroll
    for (int tap = 0; tap < 9; ++tap) {
      const int dy = tap / 3, dx = tap - dy * 3;
      const int ks = cc * 9 + tap;
      bf16x8 wf = *(const bf16x8*)(wl + (size_t)(ks * 4 + w) * 512);
#pragma unroll
      for (int nf = 0; nf < 4; ++nf) {
        int ri = nf >> 1, ci = nf & 1;
        int px = ci * 16 + dx + lm;
        int lb = (((ri + dy) * 34 + px) * CH + cc * 32 + k0) * 2;
        lb ^= (px & 7) << 4;
        bf16x8 af = *(const bf16x8*)(XS + lb);
        acc[nf] = __builtin_amdgcn_mfma_f32_16x16x32_bf16(wf, af, acc[nf], 0, 0, 0);
      }
    }
  }

  // ---- transpose 64px x 64ch through LDS (aliases XS); group-planar stores ----
  __syncthreads();
  int ocb = w * 16 + r4;
#pragma unroll
  for (int nf = 0; nf < 4; ++nf) {
    int ri = nf >> 1, ci = nf & 1;
    int p = ri * 32 + ci * 16 + lm;
    bf16 t[4];
#pragma unroll
    for (int r = 0; r < 4; ++r) {
      float v = acc[nf][r] + bias[ocb + r];
      v = v > 0.f ? v : 0.1f * v;
      t[r] = __float2bfloat16(v);
    }
    *(uint2*)&TS[p * 66 + ocb] = *(const uint2*)t;
  }
  __syncthreads();
  bf16* ob = pbuf(out_id) + (size_t)b * PHW_ * 64;
#pragma unroll
  for (int it = 0; it < 2; ++it) {
    int i = it * 256 + tid;
    int pl = i >> 6, p = i & 63;
    int ri = p >> 5, xo = p & 31;
    *(uint4*)(ob + ((size_t)pl * PHW_ + (size_t)(y0 + 1 + ri) * PH_ + x0 + 1 + xo) * 8) =
        *(const uint4*)&TS[p * 66 + pl * 8];
  }
}

// ---------------- fused offset-conv + modulated deformable conv ----------------
// grid: (800, B). block 256. One 1x32 px tile.
// A2 tile staged in LDS (R11); phase 0 split into two oc-halves; gather/MFMA
// split into two gk-halves. GATHER rewritten for minimal VALU (R12):
//  - padding-aware boundary: clamp float coords to [-1,160] + min(i1,160);
//    OOB corners read the zero border with provably-zero weights (bit-exact
//    vs explicit masking since 0*finite == finite*0 == 0).
//  - closed-form g/kk from gk = t*8+u5 (no integer divides).
//  - incremental corner addressing (a01/a10/a11 = a00 + dx/dyrow).
// Weight-product and lerp orders preserved exactly (absmax must not move).
#define LO16(u) __uint_as_float((u) << 16)
#define HI16(u) __uint_as_float((u) & 0xffff0000u)

__global__ __launch_bounds__(256, 5)
void dcn_k(int x_id, int a2_id, int co_woff, const float* __restrict__ co_bias,
           int wd_off, const float* __restrict__ bias,
           float* __restrict__ outp, int xt_out_id)
{
  const bf16* xT = pbuf(x_id);
  const bf16* WD = g_WD + wd_off;               // [18][4][64][8]
  __shared__ __align__(16) char SHD[28288];
  char* A2S = SHD;                              // [3][34][64] bf16 swz, 13056B
  float* coS = (float*)(SHD + 13056);           // [112][34] f32, 15232B
  bf16* vS = (bf16*)SHD;                        // [32][332] (gather phases)
  int tid = threadIdx.x;
  int b = blockIdx.y;
  int bx = xcdswz(blockIdx.x, 100);
  int h = bx / 5;
  int w0 = (bx % 5) * 32;
  int w = tid >> 6, L = tid & 63, lm = L & 15;
  int q = L >> 4;
  int k0 = q * 8, r4 = q * 4;
  int u5 = tid >> 5;                            // gather: gk = t*8 + u5
  int p31 = tid & 31;                           // gather: pixel within tile
  const bf16* xb = xT + (size_t)b * PHW_ * 64;
  const bf16* a2 = pbuf(a2_id) + (size_t)b * PHW_ * 64;
  const bf16* wl = g_WB + co_woff + L * 8;
  float oy[9], ox[9], mk[9];

  // ---- stage A2 tile: padded rows h..h+2, px w0..w0+33, all 8 planes ----
  for (int i = tid; i < 816; i += 256) {
    int c8 = i / 102;
    int rem = i - c8 * 102;
    int r = rem / 34, px = rem - r * 34;
    uint4 v = *(const uint4*)(a2 +
        ((size_t)c8 * PHW_ + (size_t)(h + r) * PH_ + w0 + px) * 8);
    int lb = ((r * 34 + px) * 64 + c8 * 8) * 2;
    lb ^= (px & 7) << 4;
    *(uint4*)(A2S + lb) = v;
  }
  __syncthreads();

  // ---- phase 0a: CO oc 0..111 (nt 0..6), af from LDS ----
  {
    f32x4 cacc[2][2];
#pragma unroll
    for (int ci = 0; ci < 2; ++ci)
#pragma unroll
      for (int oh = 0; oh < 2; ++oh) cacc[ci][oh] = (f32x4)0.f;
#pragma unroll
    for (int cc = 0; cc < 2; ++cc) {
#pragma unroll
      for (int tap = 0; tap < 9; ++tap) {
        const int dy = tap / 3, dx = tap - dy * 3;
        const int ks = cc * 9 + tap;
        int pxa = dx + lm, pxb = 16 + dx + lm;
        int lba = (((dy * 34 + pxa) * 64 + (cc * 4 + q) * 8) * 2) ^ ((pxa & 7) << 4);
        int lbb = (((dy * 34 + pxb) * 64 + (cc * 4 + q) * 8) * 2) ^ ((pxb & 7) << 4);
        bf16x8 af0 = *(const bf16x8*)(A2S + lba);
        bf16x8 af1 = *(const bf16x8*)(A2S + lbb);
#pragma unroll
        for (int oh = 0; oh < 2; ++oh) {
          int nt = oh * 4 + w;
          if (nt < 7) {
            bf16x8 wf = *(const bf16x8*)(wl + (size_t)(ks * 14 + nt) * 512);
            cacc[0][oh] = __builtin_amdgcn_mfma_f32_16x16x32_bf16(wf, af0, cacc[0][oh], 0, 0, 0);
            cacc[1][oh] = __builtin_amdgcn_mfma_f32_16x16x32_bf16(wf, af1, cacc[1][oh], 0, 0, 0);
          }
        }
      }
    }
#pragma unroll
    for (int ci = 0; ci < 2; ++ci)
#pragma unroll
      for (int oh = 0; oh < 2; ++oh) {
        int nt = oh * 4 + w;
        if (nt < 7) {
#pragma unroll
          for (int r = 0; r < 4; ++r) {
            int oc = nt * 16 + r4 + r;       // <= 111, never sigmoid
            coS[oc * 34 + ci * 16 + lm] = cacc[ci][oh][r] + co_bias[oc];
          }
        }
      }
  }
  __syncthreads();
  // oy/ox for taps 0..6 live in channels < 112
#pragma unroll
  for (int t = 0; t < 7; ++t) {
    int idx = t * 256 + tid;
    int gk = idx >> 5, p = idx & 31;
    oy[t] = coS[(gk * 2) * 34 + p];
    ox[t] = coS[(gk * 2 + 1) * 34 + p];
  }
  __syncthreads();

  // ---- phase 0b: CO oc 112..215 (nt 7..13), af from LDS ----
  {
    f32x4 cacc[2][2];
#pragma unroll
    for (int ci = 0; ci < 2; ++ci)
#pragma unroll
      for (int oh = 0; oh < 2; ++oh) cacc[ci][oh] = (f32x4)0.f;
#pragma unroll
    for (int cc = 0; cc < 2; ++cc) {
#pragma unroll
      for (int tap = 0; tap < 9; ++tap) {
        const int dy = tap / 3, dx = tap - dy * 3;
        const int ks = cc * 9 + tap;
        int pxa = dx + lm, pxb = 16 + dx + lm;
        int lba = (((dy * 34 + pxa) * 64 + (cc * 4 + q) * 8) * 2) ^ ((pxa & 7) << 4);
        int lbb = (((dy * 34 + pxb) * 64 + (cc * 4 + q) * 8) * 2) ^ ((pxb & 7) << 4);
        bf16x8 af0 = *(const bf16x8*)(A2S + lba);
        bf16x8 af1 = *(const bf16x8*)(A2S + lbb);
#pragma unroll
        for (int oh = 0; oh < 2; ++oh) {
          int nt = 7 + oh * 4 + w;
          if (nt < 14) {
            bf16x8 wf = *(const bf16x8*)(wl + (size_t)(ks * 14 + nt) * 512);
            cacc[0][oh] = __builtin_amdgcn_mfma_f32_16x16x32_bf16(wf, af0, cacc[0][oh], 0, 0, 0);
            cacc[1][oh] = __builtin_amdgcn_mfma_f32_16x16x32_bf16(wf, af1, cacc[1][oh], 0, 0, 0);
          }
        }
      }
    }
#pragma unroll
    for (int ci = 0; ci < 2; ++ci)
#pragma unroll
      for (int oh = 0; oh < 2; ++oh) {
        int nt = 7 + oh * 4 + w;
        if (nt < 14) {
#pragma unroll
          for (int r = 0; r < 4; ++r) {
            int oc = nt * 16 + r4 + r;       // 112..223
            if (oc < 216) {
              float v = cacc[ci][oh][r] + co_bias[oc];
              if (oc >= 144) v = 1.f / (1.f + __expf(-v));
              coS[(oc - 112) * 34 + ci * 16 + lm] = v;
            }
          }
        }
      }
  }
  __syncthreads();
  // taps 7..8 oy/ox (channels 112..143) + all masks (channels 144..215)
#pragma unroll
  for (int t = 7; t < 9; ++t) {
    int idx = t * 256 + tid;
    int gk = idx >> 5, p = idx & 31;
    oy[t] = coS[(gk * 2 - 112) * 34 + p];
    ox[t] = coS[(gk * 2 + 1 - 112) * 34 + p];
  }
#pragma unroll
  for (int t = 0; t < 9; ++t) {
    int idx = t * 256 + tid;
    int gk = idx >> 5, p = idx & 31;
    mk[t] = coS[(32 + gk) * 34 + p];
  }
  __syncthreads();

  int mt = w & 1;
  int nb2 = (w >> 1) * 2;
  f32x4 acc2[2];
  acc2[0] = (f32x4)0.f; acc2[1] = (f32x4)0.f;

#define GATHER(t, gkbase) { \
    int g = (u5 >= (t)) ? (t) : (t) - 1; \
    int kk = u5 - (t) + ((u5 >= (t)) ? 0 : 9); \
    int ky = (kk * 11) >> 5; \
    int kx = kk - ky * 3; \
    float pyf = oy[t] + (float)(ky - 1 + h); \
    float pxf = ox[t] + (float)(kx - 1 + w0 + p31); \
    pyf = fminf(fmaxf(pyf, -1.f), 160.f); \
    pxf = fminf(fmaxf(pxf, -1.f), 160.f); \
    float y0f = floorf(pyf), x0f = floorf(pxf); \
    float ly = pyf - y0f, lx = pxf - x0f; \
    int iy0 = (int)y0f, ix0 = (int)x0f; \
    int dy1 = min(iy0 + 1, 160) - iy0; \
    int dx1 = min(ix0 + 1, 160) - ix0; \
    float lyi = 1.f - ly, lxi = 1.f - lx; \
    float mask = mk[t]; \
    float w00 = lyi * lxi * mask; \
    float w01 = lyi * lx * mask; \
    float w10 = ly * lxi * mask; \
    float w11 = ly * lx * mask; \
    const bf16* a00 = xb + ((size_t)g * PHW_ + (size_t)(iy0 + 1) * PH_ + (ix0 + 1)) * 8; \
    const bf16* a01 = a00 + dx1 * 8; \
    const bf16* a10 = a00 + dy1 * (PH_ * 8); \
    const bf16* a11 = a10 + dx1 * 8; \
    uint4 u00 = *(const uint4*)a00; \
    uint4 u01 = *(const uint4*)a01; \
    uint4 u10 = *(const uint4*)a10; \
    uint4 u11 = *(const uint4*)a11; \
    bf16 tmp[8]; \
    { float vlo = w00 * LO16(u00.x) + w01 * LO16(u01.x) + w10 * LO16(u10.x) + w11 * LO16(u11.x); \
      float vhi = w00 * HI16(u00.x) + w01 * HI16(u01.x) + w10 * HI16(u10.x) + w11 * HI16(u11.x); \
      tmp[0] = __float2bfloat16(vlo); tmp[1] = __float2bfloat16(vhi); } \
    { float vlo = w00 * LO16(u00.y) + w01 * LO16(u01.y) + w10 * LO16(u10.y) + w11 * LO16(u11.y); \
      float vhi = w00 * HI16(u00.y) + w01 * HI16(u01.y) + w10 * HI16(u10.y) + w11 * HI16(u11.y); \
      tmp[2] = __float2bfloat16(vlo); tmp[3] = __float2bfloat16(vhi); } \
    { float vlo = w00 * LO16(u00.z) + w01 * LO16(u01.z) + w10 * LO16(u10.z) + w11 * LO16(u11.z); \
      float vhi = w00 * HI16(u00.z) + w01 * HI16(u01.z) + w10 * HI16(u10.z) + w11 * HI16(u11.z); \
      tmp[4] = __float2bfloat16(vlo); tmp[5] = __float2bfloat16(vhi); } \
    { float vlo = w00 * LO16(u00.w) + w01 * LO16(u01.w) + w10 * LO16(u10.w) + w11 * LO16(u11.w); \
      float vhi = w00 * HI16(u00.w) + w01 * HI16(u01.w) + w10 * HI16(u10.w) + w11 * HI16(u11.w); \
      tmp[6] = __float2bfloat16(vlo); tmp[7] = __float2bfloat16(vhi); } \
    *(uint4*)&vS[p31 * 332 + ((t) * 8 + u5 - (gkbase)) * 8] = *(const uint4*)tmp; \
  }

  // ---- half 1: gk 0..39 (taps 0..4), MFMA kc 0..9 ----
#pragma unroll
  for (int t = 0; t < 5; ++t) GATHER(t, 0)
  __syncthreads();
#pragma unroll
  for (int kc = 0; kc < 10; ++kc) {
    bf16x8 a = *(const bf16x8*)&vS[(mt * 16 + lm) * 332 + (kc * 4 + q) * 8];
#pragma unroll
    for (int i = 0; i < 2; ++i) {
      bf16x8 bw = *(const bf16x8*)(WD + ((kc * 4 + nb2 + i) * 64 + L) * 8);
      acc2[i] = __builtin_amdgcn_mfma_f32_16x16x32_bf16(a, bw, acc2[i], 0, 0, 0);
    }
  }
  __syncthreads();

  // ---- half 2: gk 40..71 (taps 5..8), MFMA kc 10..17 ----
#pragma unroll
  for (int t = 5; t < 9; ++t) GATHER(t, 40)
  __syncthreads();
#pragma unroll
  for (int kc = 10; kc < 18; ++kc) {
    bf16x8 a = *(const bf16x8*)&vS[(mt * 16 + lm) * 332 + ((kc * 4 + q) - 40) * 8];
#pragma unroll
    for (int i = 0; i < 2; ++i) {
      bf16x8 bw = *(const bf16x8*)(WD + ((kc * 4 + nb2 + i) * 64 + L) * 8);
      acc2[i] = __builtin_amdgcn_mfma_f32_16x16x32_bf16(a, bw, acc2[i], 0, 0, 0);
    }
  }
  __syncthreads();
#undef GATHER

  // ---- epilogue through LDS ----
  float* outS = (float*)SHD;          // [64 oc][33]
#pragma unroll
  for (int i = 0; i < 2; ++i)
#pragma unroll
    for (int r = 0; r < 4; ++r) {
      int oc = (nb2 + i) * 16 + lm;
      int px = mt * 16 + (L >> 4) * 4 + r;
      outS[oc * 33 + px] = acc2[i][r];
    }
  __syncthreads();
  if (outp) {
    for (int i = tid; i < 2048; i += 256) {
      int oc = i >> 5, p2 = i & 31;
      float v = outS[oc * 33 + p2] + bias[oc];
      v = v > 0.f ? v : 0.1f * v;
      outp[((size_t)(b * 64 + oc) * H_ + h) * W_ + w0 + p2] = v;
    }
  }
  if (xt_out_id) {
    bf16* xt = pbuf(xt_out_id) + (size_t)b * PHW_ * 64;
    int pl = tid >> 5, p2 = tid & 31;
    bf16 t8[8];
#pragma unroll
    for (int j = 0; j < 8; ++j) {
      int c = pl * 8 + j;
      float v = outS[c * 33 + p2] + bias[c];
      v = v > 0.f ? v : 0.1f * v;
      t8[j] = __float2bfloat16(v);
    }
    *(uint4*)(xt + ((size_t)pl * PHW_ + (size_t)(h + 1) * PH_ + w0 + p2 + 1) * 8) =
        *(const uint4*)t8;
  }
}

extern "C" void kernel_launch(void* const* d_in, const int* in_sizes, int n_in,
                              void* d_out, int out_size, void* d_ws, size_t ws_size,
                              hipStream_t stream) {
  (void)in_sizes; (void)n_in; (void)out_size; (void)d_ws; (void)ws_size;
  const float* nbr    = (const float*)d_in[0];
  const float* ref    = (const float*)d_in[1];
  const float* w_off1 = (const float*)d_in[2];
  const float* b_off1 = (const float*)d_in[3];
  const float* w_off2 = (const float*)d_in[4];
  const float* b_off2 = (const float*)d_in[5];
  const float* w_co   = (const float*)d_in[6];
  const float* b_co   = (const float*)d_in[7];
  const float* w_dcn  = (const float*)d_in[8];
  const float* b_dcn  = (const float*)d_in[9];
  const float* w_coff1= (const float*)d_in[10];
  const float* b_coff1= (const float*)d_in[11];
  const float* w_coff2= (const float*)d_in[12];
  const float* b_coff2= (const float*)d_in[13];
  const float* w_cco  = (const float*)d_in[14];
  const float* b_cco  = (const float*)d_in[15];
  const float* w_cdcn = (const float*)d_in[16];
  const float* b_cdcn = (const float*)d_in[17];

  // conv weights: off1 [0,73728) off2 [73728,110592) co@NTPB14 [110592,239616)
  //               coff1 [239616,313344) coff2 [313344,350208) cco@NTPB14 [350208,479232)
  prep_wfrag<<<288, 256, 0, stream>>>(w_off1, 0, 64, 128, 1, 4);
  prep_wfrag<<<144, 256, 0, stream>>>(w_off2, 73728, 64, 64, 1, 4);
  prep_wfrag<<<504, 256, 0, stream>>>(w_co, 110592, 216, 64, 1, 14);
  prep_wfrag<<<288, 256, 0, stream>>>(w_coff1, 239616, 64, 128, 1, 4);
  prep_wfrag<<<144, 256, 0, stream>>>(w_coff2, 313344, 64, 64, 1, 4);
  prep_wfrag<<<504, 256, 0, stream>>>(w_cco, 350208, 216, 64, 1, 14);
  prep_wdcnfrag<<<144, 256, 0, stream>>>(w_dcn, 0);
  prep_wdcnfrag<<<144, 256, 0, stream>>>(w_cdcn, 36864);

  dim3 blk(256);
  float* out = (float*)d_out;
  // group-planar padded inputs
  nchw2gp_pad<<<dim3(160, 4), blk, 0, stream>>>(nbr, 1);
  nchw2gp_pad<<<dim3(160, 4), blk, 0, stream>>>(ref, 2);
  // A1 = lrelu(conv(cat(nbr,ref))); A2 = lrelu(conv(A1))
  conv_nhwc<4><<<dim3(400, 4), blk, 0, stream>>>(1, 2, 2, 0, b_off1, 3);
  conv_nhwc<2><<<dim3(400, 4), blk, 0, stream>>>(3, 3, 2, 73728, b_off2, 4);
  // F1 = lrelu(dcn(Xnbr, conv(A2)))  (fused CO)
  dcn_k<<<dim3(800, 4), blk, 0, stream>>>(1, 4, 110592, b_co, 0, b_dcn, nullptr, 5);
  // cascade
  conv_nhwc<4><<<dim3(400, 4), blk, 0, stream>>>(5, 2, 2, 239616, b_coff1, 3);
  conv_nhwc<2><<<dim3(400, 4), blk, 0, stream>>>(3, 3, 2, 313344, b_coff2, 4);
  // out = lrelu(dcn(F1, conv(A2')))  (fused CO)
  dcn_k<<<dim3(800, 4), blk, 0, stream>>>(5, 4, 350208, b_cco, 36864, b_cdcn, out, 0);
}